// Round 7
// baseline (672.130 us; speedup 1.0000x reference)
//
#include <hip/hip_runtime.h>
#include <hip/hip_bf16.h>

#define NTOK 8192
#define DIM 1024
#define NEXP 8
#define NT 256   // virtual K tiles: 16 segments (expert x half) x 16 tiles of BK=64
#define BK 64

typedef float f32x4 __attribute__((ext_vector_type(4)));
typedef short s16x8 __attribute__((ext_vector_type(8)));
typedef unsigned short u16;
typedef unsigned short u16x4 __attribute__((ext_vector_type(4)));

__device__ __forceinline__ u16 f2bf(float f) {
    __hip_bfloat16 h = __float2bfloat16(f);
    return *reinterpret_cast<u16*>(&h);
}
__device__ __forceinline__ float bf2f(u16 u) {
    unsigned v = ((unsigned)u) << 16;
    return __uint_as_float(v);
}

#define GLOAD16(gsrc, ldst)                                                     \
    __builtin_amdgcn_global_load_lds(                                           \
        (const __attribute__((address_space(1))) void*)(gsrc),                  \
        (__attribute__((address_space(3))) void*)(ldst), 16, 0, 0)

#define MFMA16(a, b, c) __builtin_amdgcn_mfma_f32_16x16x32_bf16((a), (b), (c), 0, 0, 0)

// ---------------- gates: softmax(z_flat @ Wg^T + bg) ----------------
__global__ __launch_bounds__(256) void gates_kernel(
    const float* __restrict__ zr, const float* __restrict__ zi,
    const float* __restrict__ Wg, const float* __restrict__ bg,
    float* __restrict__ gates)
{
    const int wave = threadIdx.x >> 6, lane = threadIdx.x & 63;
    const int n = blockIdx.x * 4 + wave;

    float v[32];
    const float* zrp = zr + (size_t)n * DIM;
    const float* zip = zi + (size_t)n * DIM;
#pragma unroll
    for (int j = 0; j < 16; ++j) v[j] = zrp[j * 64 + lane];
#pragma unroll
    for (int j = 0; j < 16; ++j) v[16 + j] = zip[j * 64 + lane];

    float s[NEXP];
#pragma unroll
    for (int e = 0; e < NEXP; ++e) {
        const float* wrow = Wg + (size_t)e * (2 * DIM);
        float a = 0.f;
#pragma unroll
        for (int j = 0; j < 32; ++j) a += v[j] * wrow[j * 64 + lane];
#pragma unroll
        for (int m = 32; m; m >>= 1) a += __shfl_xor(a, m);
        s[e] = a + bg[e];
    }
    float mx = s[0];
#pragma unroll
    for (int e = 1; e < NEXP; ++e) mx = fmaxf(mx, s[e]);
    float p[NEXP], sum = 0.f;
#pragma unroll
    for (int e = 0; e < NEXP; ++e) { p[e] = expf(s[e] - mx); sum += p[e]; }
    const float inv = 1.f / sum;
    if (lane == 0) {
#pragma unroll
        for (int e = 0; e < NEXP; ++e) gates[(size_t)n * NEXP + e] = p[e] * inv;
    }
}

// ---------------- fp32 -> bf16 conversion (z and W; equal element counts) ---
__global__ __launch_bounds__(256) void cvt4_kernel(
    const float* __restrict__ zr, const float* __restrict__ zi,
    const float* __restrict__ Wr, const float* __restrict__ Wi,
    u16* __restrict__ zr16, u16* __restrict__ zi16,
    u16* __restrict__ Wr16, u16* __restrict__ Wi16)
{
    const size_t total = (size_t)NEXP * DIM * DIM / 4;  // == NTOK*DIM/4
    for (size_t i = (size_t)blockIdx.x * 256 + threadIdx.x; i < total;
         i += (size_t)gridDim.x * 256) {
        f32x4 a = ((const f32x4*)zr)[i];
        f32x4 b = ((const f32x4*)zi)[i];
        f32x4 c = ((const f32x4*)Wr)[i];
        f32x4 d = ((const f32x4*)Wi)[i];
        u16x4 pa, pb, pc, pd;
#pragma unroll
        for (int j = 0; j < 4; ++j) {
            pa[j] = f2bf(a[j]); pb[j] = f2bf(b[j]);
            pc[j] = f2bf(c[j]); pd[j] = f2bf(d[j]);
        }
        ((u16x4*)zr16)[i] = pa;
        ((u16x4*)zi16)[i] = pb;
        ((u16x4*)Wr16)[i] = pc;
        ((u16x4*)Wi16)[i] = pd;
    }
}

// ---------------- main MoE GEMM: 256x256 tile, ONE barrier per K-tile --------
// 512 threads = 8 waves (2M x 4N), per-wave 128x64. Virtual K = 16 seg x 1024.
// LDS 160 KB: A dbuf 2x32KB (VALU-staged, gate*sign folded) + B tbuf 3x32KB
// (global_load_lds for t+2). NO intra-tile barriers: reads hit buf, A-writes
// hit abuf^1, B-gloads hit bbuf(t+2) -> no intra-tile cross-wave hazards.
// One tile-boundary barrier with COUNTED vmcnt(4) (B(t+2) stays in flight)
// + lgkmcnt(0). Compiler list-schedules dsr/MFMA/cvt; waves skew within the
// tile so the LDS pipe overlaps the matrix pipe (m114-style TLP).
__global__ __launch_bounds__(512, 2) void moe_gemm7(
    const u16* __restrict__ zr16, const u16* __restrict__ zi16,
    const u16* __restrict__ Wr16, const u16* __restrict__ Wi16,
    const float* __restrict__ gates, float* __restrict__ out)
{
    extern __shared__ u16 lds[];  // A: [2][16384] at 0; B: [3][16384] at 32768

    // XCD-aware remap: hw xcd = linear%8; one (bn,sel) group per XCD.
    const int linear = blockIdx.x + 32 * (blockIdx.y + 4 * blockIdx.z);
    const int grp = linear & 7;
    const int bm = linear >> 3;
    const int bn = grp & 3;
    const int sel = grp >> 2;

    const int tid = threadIdx.x;
    const int lane = tid & 63;
    const int wid = tid >> 6;
    const int wr = wid >> 2;   // 0..1
    const int wc = wid & 3;    // 0..3

    // ---- staging addressing (swizzle chunk c ^= row&7, inverse on source) ----
    const int srow = tid >> 3;
    const int schunk = (tid & 7) ^ (srow & 7);
    int arow[4], gidx[4], brow[4];
#pragma unroll
    for (int j = 0; j < 4; ++j) {
        const int gr = bm * 256 + srow + j * 64;
        arow[j] = gr * DIM + schunk * 8;
        gidx[j] = gr * NEXP;
        brow[j] = (bn * 256 + srow + j * 64) * DIM + schunk * 8;
    }

    // ---- fragment read addressing ----
    const int cg = lane >> 4;
    const int l7 = lane & 7;
    const int ach0 = (cg ^ l7) * 8;
    const int ach1 = ((4 + cg) ^ l7) * 8;
    const int arbase = (wr * 128 + (lane & 15)) * BK;
    const int brbase = (wc * 64 + (lane & 15)) * BK;

    f32x4 acc[8][4];
#pragma unroll
    for (int m = 0; m < 8; ++m)
#pragma unroll
        for (int n = 0; n < 4; ++n) acc[m][n] = (f32x4){0.f, 0.f, 0.f, 0.f};

    // ---- segment state: A side tracks tile t+1, B side tracks tile t+2 ----
    const u16* Asrc = sel ? zi16 : zr16;   // seg 0
    const u16* Bseg = Wr16;                // seg 0
    float sg[4];
#pragma unroll
    for (int j = 0; j < 4; ++j) sg[j] = gates[gidx[j]];

    // ---- prologue: A(0)->abuf0 (VALU); B(0)->bbuf0, B(1)->bbuf1 (gloads) ----
    {
        s16x8 ga[4];
#pragma unroll
        for (int j = 0; j < 4; ++j) ga[j] = *(const s16x8*)(Asrc + arow[j]);
#pragma unroll
        for (int i = 0; i < 4; ++i)
            GLOAD16(Bseg + brow[i], &lds[32768 + (i * 512 + tid) * 8]);
#pragma unroll
        for (int i = 0; i < 4; ++i)
            GLOAD16(Bseg + brow[i] + 64, &lds[32768 + 16384 + (i * 512 + tid) * 8]);
#pragma unroll
        for (int j = 0; j < 4; ++j) {
            s16x8 w;
#pragma unroll
            for (int q = 0; q < 8; ++q)
                w[q] = (short)f2bf(bf2f((u16)ga[j][q]) * sg[j]);
            *(s16x8*)&lds[(tid + j * 512) * 8] = w;
        }
        asm volatile("s_waitcnt vmcnt(4) lgkmcnt(0)" ::: "memory");  // B(0) done
        __builtin_amdgcn_s_barrier();
    }

    int br = 0;  // B read buffer = t%3
#pragma unroll 1
    for (int t = 0; t < NT; ++t) {
        const int tn1 = t + 1, tn2 = t + 2;
        if ((tn1 & 15) == 0) {  // A/gate state for tile t+1
            const int seg = tn1 >> 4;
            const int e = (seg >> 1) & 7;
            const int half = seg & 1;
            Asrc = (half ^ sel) ? zi16 : zr16;
            const float sgn = (sel == 0 && half == 1) ? -1.f : 1.f;
#pragma unroll
            for (int j = 0; j < 4; ++j) sg[j] = sgn * gates[gidx[j] + e];
        }
        if ((tn2 & 15) == 0) {  // B state for tile t+2
            const int seg = tn2 >> 4;
            const int e = (seg >> 1) & 7;
            Bseg = ((seg & 1) ? Wi16 : Wr16) + (size_t)e * DIM * DIM;
        }
        const int ka = (tn1 & 15) << 6;      // A staging k base (elems)
        const int kb = (tn2 & 15) << 6;      // B staging k base
        const int bs = (br + 2) % 3;         // B staging buffer = (t+2)%3
        const int ab = ((t & 1) << 14) + arbase;           // A read base
        const int bb = 32768 + br * 16384 + brbase;        // B read base
        const int sa = ((tn1 & 1) << 14);                  // A staging dest
        const int sbB = 32768 + bs * 16384;                // B staging dest

        // ---- issue A reg-loads (t+1) FIRST, then B gloads (t+2) ----
        s16x8 ga[4];
#pragma unroll
        for (int j = 0; j < 4; ++j) ga[j] = *(const s16x8*)(Asrc + arow[j] + ka);
        GLOAD16(Bseg + brow[0] + kb, &lds[sbB + (0 * 512 + tid) * 8]);
        GLOAD16(Bseg + brow[1] + kb, &lds[sbB + (1 * 512 + tid) * 8]);
        GLOAD16(Bseg + brow[2] + kb, &lds[sbB + (2 * 512 + tid) * 8]);
        GLOAD16(Bseg + brow[3] + kb, &lds[sbB + (3 * 512 + tid) * 8]);

        // ---- tile t compute: free-flowing dsr + MFMA (no barriers) ----
        s16x8 bf0[4], bf1[4], afr[4];
#pragma unroll
        for (int n = 0; n < 4; ++n) bf0[n] = *(const s16x8*)&lds[bb + n * 1024 + ach0];
#pragma unroll
        for (int m = 0; m < 4; ++m) afr[m] = *(const s16x8*)&lds[ab + m * 1024 + ach0];
#pragma unroll
        for (int m = 0; m < 4; ++m)
#pragma unroll
            for (int n = 0; n < 4; ++n) acc[m][n] = MFMA16(afr[m], bf0[n], acc[m][n]);

#pragma unroll
        for (int m = 0; m < 4; ++m) afr[m] = *(const s16x8*)&lds[ab + (m + 4) * 1024 + ach0];
#pragma unroll
        for (int m = 0; m < 4; ++m)
#pragma unroll
            for (int n = 0; n < 4; ++n) acc[m + 4][n] = MFMA16(afr[m], bf0[n], acc[m + 4][n]);

#pragma unroll
        for (int n = 0; n < 4; ++n) bf1[n] = *(const s16x8*)&lds[bb + n * 1024 + ach1];
#pragma unroll
        for (int m = 0; m < 4; ++m) afr[m] = *(const s16x8*)&lds[ab + m * 1024 + ach1];
        // A staging for t+1 (cvt + ds_write to abuf^1) — overlaps MFMA freely
#pragma unroll
        for (int j = 0; j < 2; ++j) {
            s16x8 w;
#pragma unroll
            for (int q = 0; q < 8; ++q)
                w[q] = (short)f2bf(bf2f((u16)ga[j][q]) * sg[j]);
            *(s16x8*)&lds[sa + (tid + j * 512) * 8] = w;
        }
#pragma unroll
        for (int m = 0; m < 4; ++m)
#pragma unroll
            for (int n = 0; n < 4; ++n) acc[m][n] = MFMA16(afr[m], bf1[n], acc[m][n]);

#pragma unroll
        for (int m = 0; m < 4; ++m) afr[m] = *(const s16x8*)&lds[ab + (m + 4) * 1024 + ach1];
#pragma unroll
        for (int j = 2; j < 4; ++j) {
            s16x8 w;
#pragma unroll
            for (int q = 0; q < 8; ++q)
                w[q] = (short)f2bf(bf2f((u16)ga[j][q]) * sg[j]);
            *(s16x8*)&lds[sa + (tid + j * 512) * 8] = w;
        }
#pragma unroll
        for (int m = 0; m < 4; ++m)
#pragma unroll
            for (int n = 0; n < 4; ++n) acc[m + 4][n] = MFMA16(afr[m], bf1[n], acc[m + 4][n]);

        // ---- tile boundary: counted drain (B(t+2) stays in flight) + barrier
        asm volatile("s_waitcnt vmcnt(4) lgkmcnt(0)" ::: "memory");
        __builtin_amdgcn_s_barrier();

        br = (br == 2) ? 0 : br + 1;
    }
    asm volatile("s_waitcnt vmcnt(0)" ::: "memory");  // retire dead prefetches

    // ---- epilogue: C[row][col], col=lane&15, row=(lane>>4)*4+j (m89 layout) ----
    float* op = out + (size_t)sel * NTOK * DIM;
    const int col0 = bn * 256 + wc * 64 + (lane & 15);
    const int row0 = bm * 256 + wr * 128 + ((lane >> 4) << 2);
#pragma unroll
    for (int m = 0; m < 8; ++m)
#pragma unroll
        for (int n = 0; n < 4; ++n)
#pragma unroll
            for (int j = 0; j < 4; ++j)
                op[(size_t)(row0 + m * 16 + j) * DIM + col0 + n * 16] = acc[m][n][j];
}

extern "C" void kernel_launch(void* const* d_in, const int* in_sizes, int n_in,
                              void* d_out, int out_size, void* d_ws, size_t ws_size,
                              hipStream_t stream) {
    const float* zr = (const float*)d_in[0];
    const float* zi = (const float*)d_in[1];
    const float* Wg = (const float*)d_in[2];
    const float* bg = (const float*)d_in[3];
    const float* Wr = (const float*)d_in[4];
    const float* Wi = (const float*)d_in[5];
    float* out = (float*)d_out;

    const size_t NELEM = (size_t)NEXP * DIM * DIM;  // == NTOK*DIM
    u16* zr16 = (u16*)d_ws;
    u16* zi16 = zr16 + NELEM;
    u16* Wr16 = zi16 + NELEM;
    u16* Wi16 = Wr16 + NELEM;
    float* gates = (float*)(Wi16 + NELEM);

    cvt4_kernel<<<2048, 256, 0, stream>>>(zr, zi, Wr, Wi, zr16, zi16, Wr16, Wi16);
    gates_kernel<<<NTOK / 4, 256, 0, stream>>>(zr, zi, Wg, bg, gates);

    hipFuncSetAttribute((const void*)moe_gemm7,
                        hipFuncAttributeMaxDynamicSharedMemorySize, 163840);
    dim3 grid(NTOK / 256, DIM / 256, 2);
    moe_gemm7<<<grid, 512, 163840, stream>>>(zr16, zi16, Wr16, Wi16, gates, out);
}

// Round 8
// 542.561 us; speedup vs baseline: 1.2388x; 1.2388x over previous
//
#include <hip/hip_runtime.h>
#include <hip/hip_bf16.h>

#define NTOK 8192
#define DIM 1024
#define NEXP 8
#define NT 256   // virtual K tiles: 16 segments (expert x half) x 16 tiles of BK=64
#define BK 64

typedef float f32x4 __attribute__((ext_vector_type(4)));
typedef short s16x8 __attribute__((ext_vector_type(8)));
typedef unsigned short u16;
typedef unsigned short u16x4 __attribute__((ext_vector_type(4)));

__device__ __forceinline__ u16 f2bf(float f) {
    __hip_bfloat16 h = __float2bfloat16(f);
    return *reinterpret_cast<u16*>(&h);
}
__device__ __forceinline__ float bf2f(u16 u) {
    unsigned v = ((unsigned)u) << 16;
    return __uint_as_float(v);
}

#define GLOAD16(gsrc, ldst)                                                     \
    __builtin_amdgcn_global_load_lds(                                           \
        (const __attribute__((address_space(1))) void*)(gsrc),                  \
        (__attribute__((address_space(3))) void*)(ldst), 16, 0, 0)

#define MFMA16(a, b, c) __builtin_amdgcn_mfma_f32_16x16x32_bf16((a), (b), (c), 0, 0, 0)
#define SGB() __builtin_amdgcn_sched_barrier(0)

// ---------------- gates: softmax(z_flat @ Wg^T + bg) ----------------
__global__ __launch_bounds__(256) void gates_kernel(
    const float* __restrict__ zr, const float* __restrict__ zi,
    const float* __restrict__ Wg, const float* __restrict__ bg,
    float* __restrict__ gates)
{
    const int wave = threadIdx.x >> 6, lane = threadIdx.x & 63;
    const int n = blockIdx.x * 4 + wave;

    float v[32];
    const float* zrp = zr + (size_t)n * DIM;
    const float* zip = zi + (size_t)n * DIM;
#pragma unroll
    for (int j = 0; j < 16; ++j) v[j] = zrp[j * 64 + lane];
#pragma unroll
    for (int j = 0; j < 16; ++j) v[16 + j] = zip[j * 64 + lane];

    float s[NEXP];
#pragma unroll
    for (int e = 0; e < NEXP; ++e) {
        const float* wrow = Wg + (size_t)e * (2 * DIM);
        float a = 0.f;
#pragma unroll
        for (int j = 0; j < 32; ++j) a += v[j] * wrow[j * 64 + lane];
#pragma unroll
        for (int m = 32; m; m >>= 1) a += __shfl_xor(a, m);
        s[e] = a + bg[e];
    }
    float mx = s[0];
#pragma unroll
    for (int e = 1; e < NEXP; ++e) mx = fmaxf(mx, s[e]);
    float p[NEXP], sum = 0.f;
#pragma unroll
    for (int e = 0; e < NEXP; ++e) { p[e] = expf(s[e] - mx); sum += p[e]; }
    const float inv = 1.f / sum;
    if (lane == 0) {
#pragma unroll
        for (int e = 0; e < NEXP; ++e) gates[(size_t)n * NEXP + e] = p[e] * inv;
    }
}

// ---------------- fp32 -> bf16 conversion (z and W; equal element counts) ---
__global__ __launch_bounds__(256) void cvt4_kernel(
    const float* __restrict__ zr, const float* __restrict__ zi,
    const float* __restrict__ Wr, const float* __restrict__ Wi,
    u16* __restrict__ zr16, u16* __restrict__ zi16,
    u16* __restrict__ Wr16, u16* __restrict__ Wi16)
{
    const size_t total = (size_t)NEXP * DIM * DIM / 4;  // == NTOK*DIM/4
    for (size_t i = (size_t)blockIdx.x * 256 + threadIdx.x; i < total;
         i += (size_t)gridDim.x * 256) {
        f32x4 a = ((const f32x4*)zr)[i];
        f32x4 b = ((const f32x4*)zi)[i];
        f32x4 c = ((const f32x4*)Wr)[i];
        f32x4 d = ((const f32x4*)Wi)[i];
        u16x4 pa, pb, pc, pd;
#pragma unroll
        for (int j = 0; j < 4; ++j) {
            pa[j] = f2bf(a[j]); pb[j] = f2bf(b[j]);
            pc[j] = f2bf(c[j]); pd[j] = f2bf(d[j]);
        }
        ((u16x4*)zr16)[i] = pa;
        ((u16x4*)zi16)[i] = pb;
        ((u16x4*)Wr16)[i] = pc;
        ((u16x4*)Wi16)[i] = pd;
    }
}

// ---------------- main MoE GEMM: pipelined 256x256 tile ----------------------
// 512 threads = 8 waves (2M x 4N), per-wave 128x64. Virtual K = 16 seg x 1024.
// LDS 160 KB: A dbuf 2x32KB (VALU cvt, gate*sign folded) + B tbuf 3x32KB
// (gload_lds for t+2). ONE s_barrier per tile. Within a tile, each MFMA
// cluster's operands were ds_read-issued BEFORE the previous cluster
// (sched_barrier pins issue order) so the LDS pipe drains UNDER the MFMA
// bursts via compiler's counted lgkmcnt. XCD map: bm-local (each XCD owns a
// 4-bm token range -> z16 slice 4MB L2-resident; B window 2MB L2-shared).
__global__ __launch_bounds__(512, 2) void moe_gemm8(
    const u16* __restrict__ zr16, const u16* __restrict__ zi16,
    const u16* __restrict__ Wr16, const u16* __restrict__ Wi16,
    const float* __restrict__ gates, float* __restrict__ out)
{
    extern __shared__ u16 lds[];  // A: [2][16384] at 0; B: [3][16384] at 32768

    // bm-local XCD remap: hw xcd = linear%8 owns bm in [xcd*4, xcd*4+4).
    const int linear = blockIdx.x + 32 * (blockIdx.y + 4 * blockIdx.z);
    const int xcd = linear & 7;
    const int bm = xcd * 4 + ((linear >> 3) & 3);
    const int grp2 = linear >> 5;   // 0..7
    const int bn = grp2 & 3;
    const int sel = grp2 >> 2;

    const int tid = threadIdx.x;
    const int lane = tid & 63;
    const int wid = tid >> 6;
    const int wr = wid >> 2;   // 0..1
    const int wc = wid & 3;    // 0..3

    // ---- staging addressing (swizzle chunk c ^= row&7, inverse on source) ----
    const int srow = tid >> 3;
    const int schunk = (tid & 7) ^ (srow & 7);
    int arow[4], gidx[4], brow[4];
#pragma unroll
    for (int j = 0; j < 4; ++j) {
        const int gr = bm * 256 + srow + j * 64;
        arow[j] = gr * DIM + schunk * 8;
        gidx[j] = gr * NEXP;
        brow[j] = (bn * 256 + srow + j * 64) * DIM + schunk * 8;
    }

    // ---- fragment read addressing ----
    const int cg = lane >> 4;
    const int l7 = lane & 7;
    const int ach0 = (cg ^ l7) * 8;
    const int ach1 = ((4 + cg) ^ l7) * 8;
    const int arbase = (wr * 128 + (lane & 15)) * BK;
    const int brbase = (wc * 64 + (lane & 15)) * BK;

    f32x4 acc[8][4];
#pragma unroll
    for (int m = 0; m < 8; ++m)
#pragma unroll
        for (int n = 0; n < 4; ++n) acc[m][n] = (f32x4){0.f, 0.f, 0.f, 0.f};

    // ---- segment state: A side tracks tile t+1, B side tracks tile t+2 ----
    const u16* Asrc = sel ? zi16 : zr16;   // seg 0
    const u16* Bseg = Wr16;                // seg 0
    float sg[4];
#pragma unroll
    for (int j = 0; j < 4; ++j) sg[j] = gates[gidx[j]];

    // ---- prologue: A(0)->abuf0 (VALU); B(0)->bbuf0, B(1)->bbuf1 (gloads) ----
    {
        s16x8 ga[4];
#pragma unroll
        for (int j = 0; j < 4; ++j) ga[j] = *(const s16x8*)(Asrc + arow[j]);
#pragma unroll
        for (int i = 0; i < 4; ++i)
            GLOAD16(Bseg + brow[i], &lds[32768 + (i * 512 + tid) * 8]);
#pragma unroll
        for (int i = 0; i < 4; ++i)
            GLOAD16(Bseg + brow[i] + 64, &lds[32768 + 16384 + (i * 512 + tid) * 8]);
#pragma unroll
        for (int j = 0; j < 4; ++j) {
            s16x8 w;
#pragma unroll
            for (int q = 0; q < 8; ++q)
                w[q] = (short)f2bf(bf2f((u16)ga[j][q]) * sg[j]);
            *(s16x8*)&lds[(tid + j * 512) * 8] = w;
        }
        asm volatile("s_waitcnt vmcnt(4) lgkmcnt(0)" ::: "memory");  // B(0) done
        __builtin_amdgcn_s_barrier();
    }

    int br = 0;  // B read buffer = t%3
#pragma unroll 1
    for (int t = 0; t < NT; ++t) {
        const int tn1 = t + 1, tn2 = t + 2;
        if ((tn1 & 15) == 0) {  // A/gate state for tile t+1
            const int seg = tn1 >> 4;
            const int e = (seg >> 1) & 7;
            const int half = seg & 1;
            Asrc = (half ^ sel) ? zi16 : zr16;
            const float sgn = (sel == 0 && half == 1) ? -1.f : 1.f;
#pragma unroll
            for (int j = 0; j < 4; ++j) sg[j] = sgn * gates[gidx[j] + e];
        }
        if ((tn2 & 15) == 0) {  // B state for tile t+2
            const int seg = tn2 >> 4;
            const int e = (seg >> 1) & 7;
            Bseg = ((seg & 1) ? Wi16 : Wr16) + (size_t)e * DIM * DIM;
        }
        const int ka = (tn1 & 15) << 6;      // A staging k base (elems)
        const int kb = (tn2 & 15) << 6;      // B staging k base
        const int bs = (br + 2) % 3;         // B staging buffer = (t+2)%3
        const int ab = ((t & 1) << 14) + arbase;           // A read base
        const int bb = 32768 + br * 16384 + brbase;        // B read base
        const int sa = ((tn1 & 1) << 14);                  // A staging dest
        const int sbB = 32768 + bs * 16384;                // B staging dest

        // ---- issue A reg-loads (t+1), then B gloads (t+2) ----
        s16x8 ga[4];
#pragma unroll
        for (int j = 0; j < 4; ++j) ga[j] = *(const s16x8*)(Asrc + arow[j] + ka);
        GLOAD16(Bseg + brow[0] + kb, &lds[sbB + (0 * 512 + tid) * 8]);
        GLOAD16(Bseg + brow[1] + kb, &lds[sbB + (1 * 512 + tid) * 8]);
        GLOAD16(Bseg + brow[2] + kb, &lds[sbB + (2 * 512 + tid) * 8]);
        GLOAD16(Bseg + brow[3] + kb, &lds[sbB + (3 * 512 + tid) * 8]);

        // ---- R0 (b0, a0) + R1 (a1) issue ----
        s16x8 b0[4], a0[4], a1[4], b1[4], a2[4], a3[4];
#pragma unroll
        for (int n = 0; n < 4; ++n) b0[n] = *(const s16x8*)&lds[bb + n * 1024 + ach0];
#pragma unroll
        for (int m = 0; m < 4; ++m) a0[m] = *(const s16x8*)&lds[ab + m * 1024 + ach0];
#pragma unroll
        for (int m = 0; m < 4; ++m) a1[m] = *(const s16x8*)&lds[ab + (m + 4) * 1024 + ach0];
        SGB();
        // ---- MFMA0: a0 x b0 (R1 drains underneath) ----
        __builtin_amdgcn_s_setprio(1);
#pragma unroll
        for (int m = 0; m < 4; ++m)
#pragma unroll
            for (int n = 0; n < 4; ++n) acc[m][n] = MFMA16(a0[m], b0[n], acc[m][n]);
        __builtin_amdgcn_s_setprio(0);

        // ---- R2 (b1, a2) issue ----
#pragma unroll
        for (int n = 0; n < 4; ++n) b1[n] = *(const s16x8*)&lds[bb + n * 1024 + ach1];
#pragma unroll
        for (int m = 0; m < 4; ++m) a2[m] = *(const s16x8*)&lds[ab + m * 1024 + ach1];
        SGB();
        // ---- MFMA1: a1 x b0 (R2 drains underneath) ----
        __builtin_amdgcn_s_setprio(1);
#pragma unroll
        for (int m = 0; m < 4; ++m)
#pragma unroll
            for (int n = 0; n < 4; ++n) acc[m + 4][n] = MFMA16(a1[m], b0[n], acc[m + 4][n]);
        __builtin_amdgcn_s_setprio(0);

        // ---- A cvt j=0,1 + writes; R3 (a3) issue ----
#pragma unroll
        for (int j = 0; j < 2; ++j) {
            s16x8 w;
#pragma unroll
            for (int q = 0; q < 8; ++q)
                w[q] = (short)f2bf(bf2f((u16)ga[j][q]) * sg[j]);
            *(s16x8*)&lds[sa + (tid + j * 512) * 8] = w;
        }
#pragma unroll
        for (int m = 0; m < 4; ++m) a3[m] = *(const s16x8*)&lds[ab + (m + 4) * 1024 + ach1];
        SGB();
        // ---- MFMA2: a2 x b1 (writes + R3 drain underneath) ----
        __builtin_amdgcn_s_setprio(1);
#pragma unroll
        for (int m = 0; m < 4; ++m)
#pragma unroll
            for (int n = 0; n < 4; ++n) acc[m][n] = MFMA16(a2[m], b1[n], acc[m][n]);
        __builtin_amdgcn_s_setprio(0);

        // ---- A cvt j=2,3 + writes; MFMA3: a3 x b1 ----
#pragma unroll
        for (int j = 2; j < 4; ++j) {
            s16x8 w;
#pragma unroll
            for (int q = 0; q < 8; ++q)
                w[q] = (short)f2bf(bf2f((u16)ga[j][q]) * sg[j]);
            *(s16x8*)&lds[sa + (tid + j * 512) * 8] = w;
        }
        __builtin_amdgcn_s_setprio(1);
#pragma unroll
        for (int m = 0; m < 4; ++m)
#pragma unroll
            for (int n = 0; n < 4; ++n) acc[m + 4][n] = MFMA16(a3[m], b1[n], acc[m + 4][n]);
        __builtin_amdgcn_s_setprio(0);

        // ---- tile boundary: counted vmcnt (B(t+2) in flight) + full lgkm ----
        asm volatile("s_waitcnt vmcnt(4) lgkmcnt(0)" ::: "memory");
        __builtin_amdgcn_s_barrier();

        br = (br == 2) ? 0 : br + 1;
    }
    asm volatile("s_waitcnt vmcnt(0)" ::: "memory");  // retire dead prefetches

    // ---- epilogue: C[row][col], col=lane&15, row=(lane>>4)*4+j (m89 layout) ----
    float* op = out + (size_t)sel * NTOK * DIM;
    const int col0 = bn * 256 + wc * 64 + (lane & 15);
    const int row0 = bm * 256 + wr * 128 + ((lane >> 4) << 2);
#pragma unroll
    for (int m = 0; m < 8; ++m)
#pragma unroll
        for (int n = 0; n < 4; ++n)
#pragma unroll
            for (int j = 0; j < 4; ++j)
                op[(size_t)(row0 + m * 16 + j) * DIM + col0 + n * 16] = acc[m][n][j];
}

extern "C" void kernel_launch(void* const* d_in, const int* in_sizes, int n_in,
                              void* d_out, int out_size, void* d_ws, size_t ws_size,
                              hipStream_t stream) {
    const float* zr = (const float*)d_in[0];
    const float* zi = (const float*)d_in[1];
    const float* Wg = (const float*)d_in[2];
    const float* bg = (const float*)d_in[3];
    const float* Wr = (const float*)d_in[4];
    const float* Wi = (const float*)d_in[5];
    float* out = (float*)d_out;

    const size_t NELEM = (size_t)NEXP * DIM * DIM;  // == NTOK*DIM
    u16* zr16 = (u16*)d_ws;
    u16* zi16 = zr16 + NELEM;
    u16* Wr16 = zi16 + NELEM;
    u16* Wi16 = Wr16 + NELEM;
    float* gates = (float*)(Wi16 + NELEM);

    cvt4_kernel<<<2048, 256, 0, stream>>>(zr, zi, Wr, Wi, zr16, zi16, Wr16, Wi16);
    gates_kernel<<<NTOK / 4, 256, 0, stream>>>(zr, zi, Wg, bg, gates);

    hipFuncSetAttribute((const void*)moe_gemm8,
                        hipFuncAttributeMaxDynamicSharedMemorySize, 163840);
    dim3 grid(NTOK / 256, DIM / 256, 2);
    moe_gemm8<<<grid, 512, 163840, stream>>>(zr16, zi16, Wr16, Wi16, gates, out);
}